// Round 1
// baseline (95.308 us; speedup 1.0000x reference)
//
#include <hip/hip_runtime.h>
#include <math.h>

// ---------------------------------------------------------------------------
// Algebraic collapse of the reference:
//   tokens are rank-1 in the scalar feature => q_i = a_i*u_q + c_q etc.
//   score_ij = (a_i b_j (u_q.u_k) + a_i(u_q.c_k) + b_j(c_q.u_k) + c_q.c_k)/sqrt(E)
//   softmax over keys drops terms constant in the key index.
//   attn output = s_i*u_v + c_v  with s_i = sum_j attn_ij * feat_j (scalar!)
//   out_proj / mean / Wf are linear => final scalar:
//       y = c0 + c1*S_AB + c2*S_BA,  out = leaky_relu(y)
// 7 scalar constants precomputed from weights in a one-block prologue.
// ---------------------------------------------------------------------------

__global__ void precompute_consts(
    const float* __restrict__ WA, const float* __restrict__ bA,
    const float* __restrict__ WB, const float* __restrict__ bB,
    const float* __restrict__ WiAB, const float* __restrict__ biAB,
    const float* __restrict__ WoAB, const float* __restrict__ boAB,
    const float* __restrict__ WiBA, const float* __restrict__ biBA,
    const float* __restrict__ WoBA, const float* __restrict__ boBA,
    const float* __restrict__ Wf, const float* __restrict__ bf,
    float* __restrict__ consts)
{
    // side 0 = AB (queries from A tokens, kv from B tokens)
    // side 1 = BA (queries from B tokens, kv from A tokens)
    __shared__ float uq[2][32], uk[2][32], cq[2][32], uv[2][32], cv[2][32];
    __shared__ float p[2][32], r[2][32];
    const int e = threadIdx.x;
    if (e < 32) {
        float s_uq = 0.f, s_uk = 0.f, s_cq = 0.f, s_uv = 0.f, s_cv = 0.f;
        for (int d = 0; d < 32; ++d) {
            const float wq = WiAB[e * 32 + d];
            const float wk = WiAB[(32 + e) * 32 + d];
            const float wv = WiAB[(64 + e) * 32 + d];
            s_uq += wq * WA[d];   // u_q = Wq @ wA
            s_cq += wq * bA[d];   // c_q = Wq @ bA (+bq below)
            s_uk += wk * WB[d];   // u_k = Wk @ wB
            s_uv += wv * WB[d];   // u_v = Wv @ wB
            s_cv += wv * bB[d];   // c_v = Wv @ bB (+bv below)
        }
        uq[0][e] = s_uq; uk[0][e] = s_uk; cq[0][e] = s_cq + biAB[e];
        uv[0][e] = s_uv; cv[0][e] = s_cv + biAB[64 + e];

        s_uq = 0.f; s_uk = 0.f; s_cq = 0.f; s_uv = 0.f; s_cv = 0.f;
        for (int d = 0; d < 32; ++d) {
            const float wq = WiBA[e * 32 + d];
            const float wk = WiBA[(32 + e) * 32 + d];
            const float wv = WiBA[(64 + e) * 32 + d];
            s_uq += wq * WB[d];
            s_cq += wq * bB[d];
            s_uk += wk * WA[d];
            s_uv += wv * WA[d];
            s_cv += wv * bA[d];
        }
        uq[1][e] = s_uq; uk[1][e] = s_uk; cq[1][e] = s_cq + biBA[e];
        uv[1][e] = s_uv; cv[1][e] = s_cv + biBA[64 + e];
    }
    __syncthreads();
    if (e < 32) {
        float pAB = 0.f, rAB = 0.f, pBA = 0.f, rBA = 0.f;
        for (int d = 0; d < 32; ++d) {
            pAB += WoAB[e * 32 + d] * uv[0][d];
            rAB += WoAB[e * 32 + d] * cv[0][d];
            pBA += WoBA[e * 32 + d] * uv[1][d];
            rBA += WoBA[e * 32 + d] * cv[1][d];
        }
        p[0][e] = pAB; r[0][e] = rAB + boAB[e];
        p[1][e] = pBA; r[1][e] = rBA + boBA[e];
    }
    __syncthreads();
    if (e == 0) {
        float aAB = 0.f, gAB = 0.f, aBA = 0.f, gBA = 0.f;
        float c1 = 0.f, c2 = 0.f, c0 = 0.f;
        for (int d = 0; d < 32; ++d) {
            aAB += uq[0][d] * uk[0][d];
            gAB += cq[0][d] * uk[0][d];
            aBA += uq[1][d] * uk[1][d];
            gBA += cq[1][d] * uk[1][d];
            c1  += Wf[d] * p[0][d];
            c2  += Wf[d] * p[1][d];
            c0  += Wf[d] * (r[0][d] + r[1][d]);
        }
        const float inv_sqrt_e = 0.17677669529663688f; // 1/sqrt(32)
        consts[0] = aAB * inv_sqrt_e;   // kalpha_AB
        consts[1] = gAB * inv_sqrt_e;   // kgamma_AB
        consts[2] = aBA * inv_sqrt_e;   // kalpha_BA
        consts[3] = gBA * inv_sqrt_e;   // kgamma_BA
        consts[4] = 0.5f * c0 + bf[0];  // c0
        consts[5] = 0.5f * c1;          // c1 (scales S_AB)
        consts[6] = 0.5f * c2;          // c2 (scales S_BA)
    }
}

__device__ __forceinline__ float sigmoidf_(float x) {
    return 1.0f / (1.0f + expf(-x));
}

__global__ void fused_main(const float* __restrict__ Af,  // [n,3]
                           const float* __restrict__ Bf,  // [n,2]
                           const float* __restrict__ consts,
                           float* __restrict__ out, int n)
{
    const float kaAB = consts[0], kgAB = consts[1];
    const float kaBA = consts[2], kgBA = consts[3];
    const float c0 = consts[4], c1 = consts[5], c2 = consts[6];

    const int i = blockIdx.x * blockDim.x + threadIdx.x;
    if (i >= n) return;

    const float a0 = Af[3 * i + 0];
    const float a1 = Af[3 * i + 1];
    const float a2 = Af[3 * i + 2];
    const float2 bb = *reinterpret_cast<const float2*>(Bf + 2 * i);
    const float b0 = bb.x, b1 = bb.y;

    // --- S_AB: 3 queries (a_i), 2 keys (b_j); 2-key softmax == sigmoid ---
    const float dB = b0 - b1;
    const float s0 = b1 + dB * sigmoidf_(dB * (kaAB * a0 + kgAB));
    const float s1 = b1 + dB * sigmoidf_(dB * (kaAB * a1 + kgAB));
    const float s2 = b1 + dB * sigmoidf_(dB * (kaAB * a2 + kgAB));
    const float S_AB = (s0 + s1 + s2) * (1.0f / 3.0f);

    // --- S_BA: 2 queries (b_j), 3 keys (a_i) ---
    float S_BA = 0.f;
    #pragma unroll
    for (int j = 0; j < 2; ++j) {
        const float bj = (j == 0) ? b0 : b1;
        const float c = kaBA * bj + kgBA;
        const float l0 = a0 * c, l1 = a1 * c, l2 = a2 * c;
        const float m = fmaxf(l0, fmaxf(l1, l2));
        const float e0 = expf(l0 - m), e1 = expf(l1 - m), e2 = expf(l2 - m);
        S_BA += (e0 * a0 + e1 * a1 + e2 * a2) / (e0 + e1 + e2);
    }
    S_BA *= 0.5f;

    const float y = c0 + c1 * S_AB + c2 * S_BA;
    out[i] = (y >= 0.f) ? y : 0.01f * y;
}

extern "C" void kernel_launch(void* const* d_in, const int* in_sizes, int n_in,
                              void* d_out, int out_size, void* d_ws, size_t ws_size,
                              hipStream_t stream) {
    const float* groupA = (const float*)d_in[0];   // [B,3]
    const float* groupB = (const float*)d_in[1];   // [B,2]
    const float* WA   = (const float*)d_in[2];     // [32,1]
    const float* bA   = (const float*)d_in[3];     // [32]
    const float* WB   = (const float*)d_in[4];
    const float* bB   = (const float*)d_in[5];
    const float* WiAB = (const float*)d_in[6];     // [96,32]
    const float* biAB = (const float*)d_in[7];     // [96]
    const float* WoAB = (const float*)d_in[8];     // [32,32]
    const float* boAB = (const float*)d_in[9];     // [32]
    const float* WiBA = (const float*)d_in[10];
    const float* biBA = (const float*)d_in[11];
    const float* WoBA = (const float*)d_in[12];
    const float* boBA = (const float*)d_in[13];
    const float* Wf   = (const float*)d_in[14];    // [1,32]
    const float* bf   = (const float*)d_in[15];    // [1]

    float* out = (float*)d_out;
    float* consts = (float*)d_ws;                  // 7 floats

    const int n = in_sizes[0] / 3;                 // B

    precompute_consts<<<1, 64, 0, stream>>>(
        WA, bA, WB, bB, WiAB, biAB, WoAB, boAB,
        WiBA, biBA, WoBA, boBA, Wf, bf, consts);

    const int block = 256;
    const int grid = (n + block - 1) / block;
    fused_main<<<grid, block, 0, stream>>>(groupA, groupB, consts, out, n);
}